// Round 4
// baseline (47223.508 us; speedup 1.0000x reference)
//
#include <hip/hip_runtime.h>
#include <math.h>

#define B_  32
#define T_  512
#define H_  512
#define A_  128
#define VD_ 512
#define V_  32000
#define GRID 512
#define NCHUNK 500   // 64-v logits chunks

__device__ __forceinline__ float sigf(float x){ return 1.f/(1.f+expf(-x)); }
__device__ __forceinline__ float dot4(float4 a, float4 b){ return a.x*b.x+a.y*b.y+a.z*b.z+a.w*b.w; }

struct DecArgs {
  const float *key, *value, *W_emb, *b_proj, *Wq, *bq, *W_ih, *W_hh, *b_ih, *b_hh, *Wm, *bm, *h00, *c00;
  const int* src_lens;
  float* out;
  float *hA, *hB, *c, *ctx, *en, *proj, *logits, *lse, *pm, *ps, *wqT;
  int *pidx, *idx;
  int* bar;   // [grp*32] 32 group counters, [1024] master, [1056] gen
  int L;
};

// ---------------- device-scope two-level grid barrier (512 blocks, 32 grp x 16)
__device__ __forceinline__ void gbar(int* bar) {
  __syncthreads();
  if (threadIdx.x == 0) {
    int* gen = bar + 1056;
    int g = __hip_atomic_load(gen, __ATOMIC_RELAXED, __HIP_MEMORY_SCOPE_AGENT);
    int grp = blockIdx.x & 31;
    int t = __hip_atomic_fetch_add(bar + grp*32, 1, __ATOMIC_ACQ_REL, __HIP_MEMORY_SCOPE_AGENT);
    bool rel = false;
    if (t == 15) {
      __hip_atomic_store(bar + grp*32, 0, __ATOMIC_RELAXED, __HIP_MEMORY_SCOPE_AGENT);
      int tm = __hip_atomic_fetch_add(bar + 1024, 1, __ATOMIC_ACQ_REL, __HIP_MEMORY_SCOPE_AGENT);
      if (tm == 31) {
        __hip_atomic_store(bar + 1024, 0, __ATOMIC_RELAXED, __HIP_MEMORY_SCOPE_AGENT);
        __hip_atomic_fetch_add(gen, 1, __ATOMIC_RELEASE, __HIP_MEMORY_SCOPE_AGENT);
        rel = true;
      }
    }
    if (!rel) {
      while (__hip_atomic_load(gen, __ATOMIC_ACQUIRE, __HIP_MEMORY_SCOPE_AGENT) == g)
        __builtin_amdgcn_s_sleep(2);
    }
  }
  __syncthreads();
}

// ---------------- P1: gates + LSTM cell (blocks 0..255; block covers 2 t-cols)
__device__ __forceinline__ void phase1(const DecArgs& P, const float* hin, float* hout,
                                       int bid, int tid, float* sf) {
  if (bid >= 256) return;
  int g = tid >> 6, tl = (tid >> 5) & 1, b = tid & 31;
  int t = bid*2 + tl;
  int j = g*512 + t;
  const float4* emb = (const float4*)(P.W_emb + (size_t)P.idx[b]*H_);
  const float4* cx  = (const float4*)(P.ctx + b*VD_);
  const float4* hv  = (const float4*)(hin + b*H_);
  const float4* wi  = (const float4*)(P.W_ih + (size_t)j*(H_+VD_));
  const float4* wc  = wi + 128;
  const float4* wh  = (const float4*)(P.W_hh + (size_t)j*H_);
  float acc = P.b_ih[j] + P.b_hh[j];
#pragma unroll 8
  for (int k = 0; k < 128; k++) acc += dot4(wi[k], emb[k]);
#pragma unroll 8
  for (int k = 0; k < 128; k++) acc += dot4(wc[k], cx[k]);
#pragma unroll 8
  for (int k = 0; k < 128; k++) acc += dot4(wh[k], hv[k]);
  sf[(tl*32 + b)*4 + g] = acc;
  __syncthreads();
  if (tid < 64) {
    int tl2 = tid >> 5, b2 = tid & 31;
    int t2 = bid*2 + tl2;
    float gi = sf[(tl2*32+b2)*4+0], gf = sf[(tl2*32+b2)*4+1];
    float gg = sf[(tl2*32+b2)*4+2], go = sf[(tl2*32+b2)*4+3];
    float c0 = P.c[b2*H_ + t2];
    float c1 = sigf(gf)*c0 + sigf(gi)*tanhf(gg);
    P.c[b2*H_ + t2] = c1;
    hout[b2*H_ + t2] = sigf(go)*tanhf(c1);
  }
}

// ---------------- P2: q (per-block from WqT) + energy t-slice -> en  (+out[sidx])
// block = ts*32 + b ; ts 0..15 owns t-range [ts*32, ts*32+32)
__device__ __forceinline__ void phase2(const DecArgs& P, const float* hsrc,
                                       int bid, int tid, float* smem, int sidx) {
  int b = bid & 31, ts = bid >> 5;
  float* h_sh = smem;          // 512
  float* qred = smem + 512;    // 256
  float* q_sh = smem + 768;    // 128
  float* red  = smem + 896;    // 256
  h_sh[tid]       = hsrc[b*H_ + tid];
  h_sh[tid + 256] = hsrc[b*H_ + tid + 256];
  __syncthreads();
  {
    int a = tid & 127, hf = tid >> 7;
    const float* wq = P.wqT + (size_t)hf*256*128 + a;   // wqT[k][a], k = hf*256..
    float acc = 0.f;
#pragma unroll 8
    for (int k = 0; k < 256; k++) acc += h_sh[hf*256 + k] * wq[(size_t)k*128];
    qred[hf*128 + a] = acc;
  }
  __syncthreads();
  if (tid < 128) q_sh[tid] = qred[tid] + qred[128 + tid] + P.bq[tid];
  __syncthreads();
  {
    int tl = tid >> 3, ah = tid & 7;
    int t = ts*32 + tl;
    const float* kp = P.key + (size_t)b*A_*T_ + t;
    float e = 0.f;
#pragma unroll
    for (int j = 0; j < 16; j++) { int a = ah*16 + j; e += q_sh[a] * kp[(size_t)a*T_]; }
    red[tid] = e;
  }
  __syncthreads();
  if ((tid & 7) < 4) red[tid] += red[tid + 4];
  __syncthreads();
  if ((tid & 7) < 2) red[tid] += red[tid + 2];
  __syncthreads();
  if ((tid & 7) == 0) P.en[b*T_ + ts*32 + (tid >> 3)] = red[tid] + red[tid + 1];
  // out[sidx] (uses logits+lse of previous step, still intact)
  if (sidx >= 0) {
    float l = P.lse[b];
    const float4* lg = (const float4*)(P.logits + (size_t)b*V_ + ts*2000);
    float4* o4 = (float4*)(P.out + ((size_t)b*P.L + sidx)*V_ + ts*2000);
    for (int i = tid; i < 500; i += 256) {
      float4 x = lg[i];
      o4[i] = make_float4(x.x-l, x.y-l, x.z-l, x.w-l);
    }
  }
}

// ---------------- P3: masked softmax (from en) + ctx slice
// block = vs*32 + b ; vs 0..15 owns ctx cols [vs*32, vs*32+32)
__device__ __forceinline__ void phase3(const DecArgs& P, int bid, int tid, float* smem) {
  int b = bid & 31, vs = bid >> 5;
  float* e_sh = smem;          // 512
  float* att  = smem + 512;    // 512
  float* red  = smem + 1024;   // 256
  e_sh[tid]       = P.en[b*T_ + tid];
  e_sh[tid + 256] = P.en[b*T_ + tid + 256];
  __syncthreads();
  red[tid] = fmaxf(e_sh[tid], e_sh[tid + 256]);
  __syncthreads();
  for (int s2 = 128; s2 > 0; s2 >>= 1) { if (tid < s2) red[tid] = fmaxf(red[tid], red[tid+s2]); __syncthreads(); }
  float M = red[0];
  __syncthreads();
  int len = P.src_lens[b];
  float p0 = (tid       < len) ? expf(e_sh[tid] - M) : 0.f;
  float p1 = (tid + 256 < len) ? expf(e_sh[tid+256] - M) : 0.f;
  red[tid] = p0 + p1;
  __syncthreads();
  for (int s2 = 128; s2 > 0; s2 >>= 1) { if (tid < s2) red[tid] += red[tid+s2]; __syncthreads(); }
  float rS = 1.f / red[0];
  att[tid] = p0 * rS; att[tid + 256] = p1 * rS;
  __syncthreads();
  int vl = tid & 31, tq = tid >> 5;
  const float* vp = P.value + (size_t)b*T_*VD_ + vs*32 + vl;
  float acc = 0.f;
#pragma unroll 8
  for (int t = tq*64; t < tq*64 + 64; t++) acc += att[t] * vp[(size_t)t*VD_];
  red[tid] = acc;
  __syncthreads();
  if (tid < 32) {
    float s = 0.f;
#pragma unroll
    for (int j = 0; j < 8; j++) s += red[j*32 + tid];
    P.ctx[b*VD_ + vs*32 + tid] = s;
  }
}

// ---------------- P4: proj row m = leaky_relu([c1,ctx1]@Wm[m] + bm)  (block = m)
__device__ __forceinline__ void phase4(const DecArgs& P, int bid, int tid, float* smem) {
  int m = bid;
  int b2 = tid >> 3, kh = tid & 7;
  const float4* x4 = (kh < 4) ? ((const float4*)(P.c + b2*H_) + kh*32)
                              : ((const float4*)(P.ctx + b2*VD_) + (kh-4)*32);
  const float4* w4 = (const float4*)(P.Wm + (size_t)m*(H_+VD_)) + kh*32;
  float acc = 0.f;
#pragma unroll 8
  for (int i = 0; i < 32; i++) acc += dot4(w4[i], x4[i]);
  smem[tid] = acc;
  __syncthreads();
  if ((tid & 7) == 0) {
    float s = 0.f;
#pragma unroll
    for (int j = 0; j < 8; j++) s += smem[tid + j];
    s += P.bm[m];
    P.proj[b2*H_ + m] = (s > 0.f) ? s : 0.01f*s;
  }
}

// ---------------- P5: logits chunk (64 v) via LDS-tiled GEMV + online partials
__device__ __forceinline__ void phase5(const DecArgs& P, int bid, int tid, float* smem) {
  float* p_sh = smem;            // 32 rows x 65 float4 (padded) = 8320 floats
  float* w_sh = smem + 8320;     // 16 rows x 64 float4 = 4096 floats
  float4* p4s = (float4*)p_sh;
  float4* w4s = (float4*)w_sh;
  int b = tid & 31, vl = tid >> 5;
  bool act = bid < NCHUNK;
  int vbase = bid*64;
  float acc[8];
#pragma unroll
  for (int i = 0; i < 8; i++) acc[i] = 0.f;

  for (int kh = 0; kh < 2; kh++) {
    __syncthreads();   // previous users of p_sh/w_sh done
    if (act) {  // stage proj k-half: [32][64 f4] -> padded rows of 65 f4
      const float4* pr = (const float4*)P.proj + (size_t)(tid>>3)*128 + kh*64 + (tid&7)*8;
      float4* pw = p4s + (tid>>3)*65 + (tid&7)*8;
#pragma unroll
      for (int j = 0; j < 8; j++) pw[j] = pr[j];
    }
    for (int sub = 0; sub < 4; sub++) {
      if (sub) __syncthreads();
      if (act) {  // stage 16 W_emb rows (k-half slice), coalesced
        int lr = tid >> 4, i = tid & 15;
        int gr = vbase + sub*16 + lr;
        const float4* gw = (const float4*)P.W_emb + (size_t)gr*128 + kh*64;
#pragma unroll
        for (int j = 0; j < 4; j++) w4s[lr*64 + i + 16*j] = gw[i + 16*j];
      }
      __syncthreads();
      if (act) {
        const float4* pr = p4s + b*65;
        const float4* w0 = w4s + (vl*2)*64;
        const float4* w1 = w4s + (vl*2+1)*64;
        float a0 = acc[sub*2], a1 = acc[sub*2+1];
#pragma unroll 8
        for (int k4 = 0; k4 < 64; k4++) {
          float4 p4 = pr[k4];
          a0 += dot4(w0[k4], p4);
          a1 += dot4(w1[k4], p4);
        }
        acc[sub*2] = a0; acc[sub*2+1] = a1;
      }
    }
  }
  __syncthreads();   // before aliasing smem for reduction
  float* rm = smem; float* rs = smem + 256; int* ri = (int*)(smem + 512);
  if (act) {
    float m = -INFINITY, s = 0.f; int mi = 0;
#pragma unroll
    for (int i = 0; i < 8; i++) {          // ascending v within thread
      int sub = i >> 1, r = i & 1;
      int v = vbase + sub*16 + vl*2 + r;
      float x = acc[i] + P.b_proj[v];
      P.logits[(size_t)b*V_ + v] = x;
      if (x > m) { s = s*expf(m - x) + 1.f; m = x; mi = v; }
      else       { s += expf(x - m); }     // ties keep earlier v
    }
    rm[vl*32 + b] = m; rs[vl*32 + b] = s; ri[vl*32 + b] = mi;
  }
  __syncthreads();
  if (act && tid < 32) {
    int bb = tid;
    float M = rm[bb], S = rs[bb]; int I = ri[bb];
#pragma unroll
    for (int g = 1; g < 8; g++) {          // ascending vl => ascending v-pairs
      float m2 = rm[g*32+bb], s2 = rs[g*32+bb]; int i2 = ri[g*32+bb];
      if (m2 > M)       { S = S*expf(M - m2) + s2; M = m2; I = i2; }
      else if (m2 == M) { S += s2; I = min(I, i2); }
      else              { S += s2*expf(m2 - M); }
    }
    P.pm[bid*32 + bb] = M; P.ps[bid*32 + bb] = S; P.pidx[bid*32 + bb] = I;
  }
}

// ---------------- P6: merge chunk partials -> lse[b], idx[b]  (blocks 0..31)
__device__ __forceinline__ void phase6(const DecArgs& P, int bid, int tid, float* smem) {
  if (bid >= B_) return;
  float* sfm = smem; float* sfs = smem + 256; int* sii = (int*)(smem + 512);
  int b = bid;
  float M = P.pm[tid*32 + b], S = P.ps[tid*32 + b]; int I = P.pidx[tid*32 + b];
  int c2 = tid + 256;
  if (c2 < NCHUNK) {
    float m2 = P.pm[c2*32+b], s2 = P.ps[c2*32+b]; int i2 = P.pidx[c2*32+b];
    if (m2 > M)       { S = S*expf(M - m2) + s2; M = m2; I = i2; }
    else if (m2 == M) { S += s2; I = min(I, i2); }
    else              { S += s2*expf(m2 - M); }
  }
  sfm[tid] = M; sfs[tid] = S; sii[tid] = I;
  __syncthreads();
  for (int st = 128; st > 0; st >>= 1) {
    if (tid < st) {
      float m1 = sfm[tid], s1 = sfs[tid]; int i1 = sii[tid];
      float m2 = sfm[tid+st], s2 = sfs[tid+st]; int i2 = sii[tid+st];
      float Mn, Sn; int In;
      if (m2 > m1)      { Mn = m2; Sn = s1*expf(m1-m2) + s2; In = i2; }
      else if (m2 < m1) { Mn = m1; Sn = s1 + s2*expf(m2-m1); In = i1; }
      else              { Mn = m1; Sn = s1 + s2; In = min(i1, i2); }
      sfm[tid] = Mn; sfs[tid] = Sn; sii[tid] = In;
    }
    __syncthreads();
  }
  if (tid == 0) { P.lse[b] = sfm[0] + logf(sfs[0]); P.idx[b] = sii[0]; }
}

// ---------------- final out write (step L-1), 512 blocks
__device__ __forceinline__ void phase_out_final(const DecArgs& P, int bid, int tid) {
  int b = bid & 31, ts = bid >> 5;
  float l = P.lse[b];
  const float4* lg = (const float4*)(P.logits + (size_t)b*V_ + ts*2000);
  float4* o4 = (float4*)(P.out + ((size_t)b*P.L + (P.L-1))*V_ + ts*2000);
  for (int i = tid; i < 500; i += 256) {
    float4 x = lg[i];
    o4[i] = make_float4(x.x-l, x.y-l, x.z-l, x.w-l);
  }
}

__global__ __launch_bounds__(256, 2) void k_decode(DecArgs P) {
  const int bid = blockIdx.x, tid = threadIdx.x;
  __shared__ float smem[12416];   // 49,664 B -> 3 blocks/CU by LDS

  // init: h, c, idx, WqT transpose
  int g = bid*256 + tid;
  if (g < B_*H_) { P.hA[g] = P.h00[g & (H_-1)]; P.c[g] = P.c00[g & (H_-1)]; }
  if (g < A_*H_) { int k = g >> 7, a = g & 127; P.wqT[g] = P.Wq[a*H_ + k]; }
  if (g < B_) P.idx[g] = 0;
  gbar(P.bar);

  // prologue attend with h0
  phase2(P, P.hA, bid, tid, smem, -1);
  gbar(P.bar);
  phase3(P, bid, tid, smem);
  gbar(P.bar);

  for (int s = 0; s < P.L; s++) {
    const float* hin  = (s & 1) ? P.hB : P.hA;
    float*       hout = (s & 1) ? P.hA : P.hB;
    phase1(P, hin, hout, bid, tid, smem);
    gbar(P.bar);
    phase2(P, hout, bid, tid, smem, s - 1);
    gbar(P.bar);
    phase3(P, bid, tid, smem);
    gbar(P.bar);
    phase4(P, bid, tid, smem);
    gbar(P.bar);
    phase5(P, bid, tid, smem);
    gbar(P.bar);
    phase6(P, bid, tid, smem);
    gbar(P.bar);
  }
  phase_out_final(P, bid, tid);
}

extern "C" void kernel_launch(void* const* d_in, const int* in_sizes, int n_in,
                              void* d_out, int out_size, void* d_ws, size_t ws_size,
                              hipStream_t stream) {
  DecArgs P;
  P.key      = (const float*)d_in[0];
  P.value    = (const float*)d_in[1];
  P.src_lens = (const int*)d_in[4];
  P.W_emb    = (const float*)d_in[5];
  P.b_proj   = (const float*)d_in[6];
  P.Wq       = (const float*)d_in[7];
  P.bq       = (const float*)d_in[8];
  P.W_ih     = (const float*)d_in[9];
  P.W_hh     = (const float*)d_in[10];
  P.b_ih     = (const float*)d_in[11];
  P.b_hh     = (const float*)d_in[12];
  P.Wm       = (const float*)d_in[13];
  P.bm       = (const float*)d_in[14];
  P.h00      = (const float*)d_in[15];
  P.c00      = (const float*)d_in[16];
  P.out      = (float*)d_out;
  P.L        = in_sizes[2] / B_;

  P.bar = (int*)d_ws;                       // 2048 ints reserved
  float* ws = (float*)d_ws + 2048;
  P.hA     = ws; ws += B_*H_;
  P.hB     = ws; ws += B_*H_;
  P.c      = ws; ws += B_*H_;
  P.ctx    = ws; ws += B_*VD_;
  P.en     = ws; ws += B_*T_;
  P.proj   = ws; ws += B_*H_;
  P.lse    = ws; ws += 32;
  P.pm     = ws; ws += NCHUNK*B_;
  P.ps     = ws; ws += NCHUNK*B_;
  P.wqT    = ws; ws += A_*H_;
  P.logits = ws; ws += (size_t)B_*V_;
  P.pidx   = (int*)ws; ws += NCHUNK*B_;
  P.idx    = (int*)ws;

  hipMemsetAsync(P.bar, 0, 2048*sizeof(int), stream);
  hipLaunchKernelGGL(k_decode, dim3(GRID), dim3(256), 0, stream, P);
}